// Round 1
// baseline (120.656 us; speedup 1.0000x reference)
//
#include <hip/hip_runtime.h>
#include <hip/hip_bf16.h>

typedef short short4v __attribute__((ext_vector_type(4)));
typedef float float4v __attribute__((ext_vector_type(4)));

__device__ __forceinline__ float bf2f(unsigned short u) {
    union { unsigned int i; float f; } t;
    t.i = ((unsigned int)u) << 16;
    return t.f;
}
__device__ __forceinline__ unsigned short f2bf(float f) {
    union { float f; unsigned int i; } t;
    t.f = f;
    unsigned int u = t.i;
    u += 0x7fffu + ((u >> 16) & 1u);   // round-to-nearest-even
    return (unsigned short)(u >> 16);
}

// ---------------------------------------------------------------------------
// Kernel 0: convert weights f32 -> bf16
// ---------------------------------------------------------------------------
__global__ __launch_bounds__(256) void prep_kernel(const float* __restrict__ wq,
                                                   const float* __restrict__ wo,
                                                   unsigned short* __restrict__ wqb,
                                                   unsigned short* __restrict__ wob) {
    int i = blockIdx.x * 256 + threadIdx.x;   // grid covers exactly 262144
    if (i < 196608) wqb[i] = f2bf(wq[i]);
    else            wob[i - 196608] = f2bf(wo[i - 196608]);
}

// ---------------------------------------------------------------------------
// Kernel 1: channel LayerNorm.  x[b][c=256][pix=1024] f32 -> xn bf16 same layout.
// block = 256 threads = 16 pixels x 16 c-groups; grid = (64 pixgroups, 16 b)
// ---------------------------------------------------------------------------
__global__ __launch_bounds__(256) void ln_kernel(const float* __restrict__ x,
                                                 const float* __restrict__ g,
                                                 unsigned short* __restrict__ xn) {
    __shared__ float s_sum[16][17];
    __shared__ float s_sq[16][17];
    const int tid = threadIdx.x;
    const int p = tid & 15;        // pixel within group
    const int cs = tid >> 4;       // c-group 0..15
    const int b = blockIdx.y;
    const int pix = blockIdx.x * 16 + p;
    const float* xb = x + ((size_t)b << 18) + pix;

    float sum = 0.f, sq = 0.f;
    #pragma unroll
    for (int cc = 0; cc < 16; ++cc) {
        int c = cs * 16 + cc;
        float v = xb[c << 10];
        sum += v; sq += v * v;
    }
    s_sum[cs][p] = sum; s_sq[cs][p] = sq;
    __syncthreads();
    float ts = 0.f, tq = 0.f;
    #pragma unroll
    for (int k = 0; k < 16; ++k) { ts += s_sum[k][p]; tq += s_sq[k][p]; }
    float mean = ts * (1.f / 256.f);
    float var  = tq * (1.f / 256.f) - mean * mean;
    float rstd = rsqrtf(var + 1e-5f);

    unsigned short* xnb = xn + ((size_t)b << 18) + pix;
    #pragma unroll
    for (int cc = 0; cc < 16; ++cc) {
        int c = cs * 16 + cc;
        float v = xb[c << 10];
        xnb[c << 10] = f2bf((v - mean) * rstd * g[c]);
    }
}

// ---------------------------------------------------------------------------
// Kernel 2/5: GEMM  C[b][M][1024] = A[M][256](bf16) * B[b][256][1024](bf16)
// 16x16x16 bf16 MFMA (classic verified layout).  BM=BN=64, BK=16, 4 waves.
// OUT_BF16=1: write bf16.  OUT_BF16=0: write f32 + residual xres.
// ---------------------------------------------------------------------------
template <int OUT_BF16>
__global__ __launch_bounds__(256) void gemm_kernel(const unsigned short* __restrict__ A,
                                                   const unsigned short* __restrict__ B,
                                                   void* __restrict__ Cout,
                                                   const float* __restrict__ xres,
                                                   int M) {
    __shared__ __align__(16) unsigned short Alds[64][20];
    __shared__ __align__(16) unsigned short Blds[64][20];   // transposed: [col][k]
    const int tid = threadIdx.x;
    const int lane = tid & 63, w = tid >> 6;
    const int l16 = lane & 15, gg = (lane >> 4) & 3;
    const int m0 = blockIdx.x * 64;
    const int n0 = blockIdx.y * 64;
    const int b  = blockIdx.z;
    const unsigned short* Bb = B + ((size_t)b << 18);

    float4v acc[4] = {{0,0,0,0},{0,0,0,0},{0,0,0,0},{0,0,0,0}};
    const int arow = tid >> 2, akq = (tid & 3) << 2;    // A tile 64x16, 4 bf16/thread
    const int bkr = tid >> 4,  bcg = (tid & 15) << 2;   // B tile 16x64, 4 bf16/thread

    for (int k0 = 0; k0 < 256; k0 += 16) {
        uint2 av = *reinterpret_cast<const uint2*>(A + (size_t)(m0 + arow) * 256 + k0 + akq);
        uint2 bv = *reinterpret_cast<const uint2*>(Bb + ((size_t)(k0 + bkr) << 10) + n0 + bcg);
        *reinterpret_cast<uint2*>(&Alds[arow][akq]) = av;
        Blds[bcg + 0][bkr] = (unsigned short)(bv.x & 0xffffu);
        Blds[bcg + 1][bkr] = (unsigned short)(bv.x >> 16);
        Blds[bcg + 2][bkr] = (unsigned short)(bv.y & 0xffffu);
        Blds[bcg + 3][bkr] = (unsigned short)(bv.y >> 16);
        __syncthreads();
        short4v af = *reinterpret_cast<const short4v*>(&Alds[16 * w + l16][4 * gg]);
        #pragma unroll
        for (int jt = 0; jt < 4; ++jt) {
            short4v bf = *reinterpret_cast<const short4v*>(&Blds[16 * jt + l16][4 * gg]);
            acc[jt] = __builtin_amdgcn_mfma_f32_16x16x16bf16_1k(af, bf, acc[jt], 0, 0, 0);
        }
        __syncthreads();
    }

    const size_t cb = ((size_t)b * (size_t)M) << 10;
    #pragma unroll
    for (int jt = 0; jt < 4; ++jt) {
        #pragma unroll
        for (int r = 0; r < 4; ++r) {
            int row = m0 + 16 * w + 4 * gg + r;
            int col = n0 + 16 * jt + l16;
            size_t idx = cb + ((size_t)row << 10) + col;
            float v = acc[jt][r];
            if (OUT_BF16) ((unsigned short*)Cout)[idx] = f2bf(v);
            else          ((float*)Cout)[idx] = v + xres[idx];
        }
    }
}

// ---------------------------------------------------------------------------
// Kernel 3: L2-normalize q,k rows (over d=64, stride 1024) in place.
// grid = (16 pixgroups, 8 = part*4+head, 16 b), block 256 = 64 pix x 4 d-groups
// ---------------------------------------------------------------------------
__global__ __launch_bounds__(256) void l2norm_kernel(unsigned short* __restrict__ qkv) {
    __shared__ float s_red[4][64];
    const int tid = threadIdx.x;
    const int p = tid & 63, dq = tid >> 6;
    const int pix = blockIdx.x * 64 + p;
    const int part = blockIdx.y >> 2, h = blockIdx.y & 3;
    const int b = blockIdx.z;
    unsigned short* base = qkv + (((size_t)(b * 768 + part * 256 + h * 64)) << 10) + pix;

    float vals[16];
    float s = 0.f;
    #pragma unroll
    for (int dd = 0; dd < 16; ++dd) {
        vals[dd] = bf2f(base[(size_t)(dq * 16 + dd) << 10]);
        s += vals[dd] * vals[dd];
    }
    s_red[dq][p] = s;
    __syncthreads();
    float tot = s_red[0][p] + s_red[1][p] + s_red[2][p] + s_red[3][p];
    float rn = rsqrtf(fmaxf(tot, 1e-24f));
    #pragma unroll
    for (int dd = 0; dd < 16; ++dd) {
        base[(size_t)(dq * 16 + dd) << 10] = f2bf(vals[dd] * rn);
    }
}

// ---------------------------------------------------------------------------
// Kernel 4: flash attention.  One block = (b, h, 64 queries).  4 waves.
// Computes S^T = khat * qhat^T so P^T is directly the B-operand of O^T = V^T P^T.
// ---------------------------------------------------------------------------
__global__ __launch_bounds__(256) void attn_kernel(const unsigned short* __restrict__ qkv,
                                                   unsigned short* __restrict__ attnout) {
    __shared__ __align__(16) unsigned short Klds[64][68];  // [j][d]
    __shared__ __align__(16) unsigned short Vlds[64][68];  // [d][j]
    const int tid = threadIdx.x;
    const int lane = tid & 63, w = tid >> 6;
    const int l16 = lane & 15, gg = (lane >> 4) & 3;
    const int q0 = blockIdx.x * 64;
    const int h = blockIdx.y;
    const int b = blockIdx.z;
    const unsigned short* Qg = qkv + (((size_t)(b * 768 + h * 64)) << 10);
    const unsigned short* Kg = Qg + ((size_t)256 << 10);
    const unsigned short* Vg = Qg + ((size_t)512 << 10);

    // per-lane qhat fragment: B[k=d][col=i], i = q0 + 16w + l16 (pre-normalized)
    short4v bq[4];
    {
        const int ig = q0 + 16 * w + l16;
        #pragma unroll
        for (int ds = 0; ds < 4; ++ds) {
            short4v t;
            #pragma unroll
            for (int ii = 0; ii < 4; ++ii)
                t[ii] = (short)Qg[((size_t)(16 * ds + 4 * gg + ii) << 10) + ig];
            bq[ds] = t;
        }
    }

    float m_run = -1e30f, lsum = 0.f;
    float4v oacc[4] = {{0,0,0,0},{0,0,0,0},{0,0,0,0},{0,0,0,0}};
    const int dL = tid >> 4;          // 0..15
    const int pg4 = (tid & 15) << 2;  // 0..60

    for (int j0 = 0; j0 < 1024; j0 += 64) {
        __syncthreads();   // previous tile's LDS readers done
        #pragma unroll
        for (int dd = 0; dd < 64; dd += 16) {
            int d = dL + dd;
            uint2 kvv = *reinterpret_cast<const uint2*>(Kg + ((size_t)d << 10) + j0 + pg4);
            Klds[pg4 + 0][d] = (unsigned short)(kvv.x & 0xffffu);
            Klds[pg4 + 1][d] = (unsigned short)(kvv.x >> 16);
            Klds[pg4 + 2][d] = (unsigned short)(kvv.y & 0xffffu);
            Klds[pg4 + 3][d] = (unsigned short)(kvv.y >> 16);
            uint2 vvv = *reinterpret_cast<const uint2*>(Vg + ((size_t)d << 10) + j0 + pg4);
            *reinterpret_cast<uint2*>(&Vlds[d][pg4]) = vvv;
        }
        __syncthreads();

        // S^T[j][i]: wave w owns i-cols [16w,16w+16); st[jt][r] = S^T[16jt+4g+r][i]
        float4v st[4] = {{0,0,0,0},{0,0,0,0},{0,0,0,0},{0,0,0,0}};
        #pragma unroll
        for (int ds = 0; ds < 4; ++ds) {
            #pragma unroll
            for (int jt = 0; jt < 4; ++jt) {
                short4v ak = *reinterpret_cast<const short4v*>(&Klds[16 * jt + l16][16 * ds + 4 * gg]);
                st[jt] = __builtin_amdgcn_mfma_f32_16x16x16bf16_1k(ak, bq[ds], st[jt], 0, 0, 0);
            }
        }

        // online softmax over j for this lane's column i
        float mloc = -1e30f;
        #pragma unroll
        for (int jt = 0; jt < 4; ++jt)
            mloc = fmaxf(mloc, fmaxf(fmaxf(st[jt][0], st[jt][1]), fmaxf(st[jt][2], st[jt][3])));
        mloc = fmaxf(mloc, __shfl_xor(mloc, 16, 64));
        mloc = fmaxf(mloc, __shfl_xor(mloc, 32, 64));
        float m_new = fmaxf(m_run, 8.f * mloc);
        float alpha = __expf(m_run - m_new);
        m_run = m_new;

        float psum = 0.f;
        short4v pf[4];
        #pragma unroll
        for (int jt = 0; jt < 4; ++jt) {
            float p0 = __expf(__fmaf_rn(8.f, st[jt][0], -m_new));
            float p1 = __expf(__fmaf_rn(8.f, st[jt][1], -m_new));
            float p2 = __expf(__fmaf_rn(8.f, st[jt][2], -m_new));
            float p3 = __expf(__fmaf_rn(8.f, st[jt][3], -m_new));
            psum += p0 + p1 + p2 + p3;
            short4v t;
            t[0] = (short)f2bf(p0); t[1] = (short)f2bf(p1);
            t[2] = (short)f2bf(p2); t[3] = (short)f2bf(p3);
            pf[jt] = t;
        }
        psum += __shfl_xor(psum, 16, 64);
        psum += __shfl_xor(psum, 32, 64);
        lsum = lsum * alpha + psum;

        #pragma unroll
        for (int dt = 0; dt < 4; ++dt) {
            oacc[dt][0] *= alpha; oacc[dt][1] *= alpha;
            oacc[dt][2] *= alpha; oacc[dt][3] *= alpha;
        }
        // O^T[d][i] += V^T[d][j] * P^T[j][i]
        #pragma unroll
        for (int jt = 0; jt < 4; ++jt) {
            #pragma unroll
            for (int dt = 0; dt < 4; ++dt) {
                short4v av = *reinterpret_cast<const short4v*>(&Vlds[16 * dt + l16][16 * jt + 4 * gg]);
                oacc[dt] = __builtin_amdgcn_mfma_f32_16x16x16bf16_1k(av, pf[jt], oacc[dt], 0, 0, 0);
            }
        }
    }

    float inv = 1.f / lsum;
    unsigned short* outb = attnout + (((size_t)(b * 256 + h * 64)) << 10) + q0;
    #pragma unroll
    for (int dt = 0; dt < 4; ++dt) {
        #pragma unroll
        for (int r = 0; r < 4; ++r) {
            int d = 16 * dt + 4 * gg + r;
            outb[((size_t)d << 10) + 16 * w + l16] = f2bf(oacc[dt][r] * inv);
        }
    }
}

// ---------------------------------------------------------------------------
extern "C" void kernel_launch(void* const* d_in, const int* in_sizes, int n_in,
                              void* d_out, int out_size, void* d_ws, size_t ws_size,
                              hipStream_t stream) {
    const float* x  = (const float*)d_in[0];
    const float* g  = (const float*)d_in[1];
    const float* wq = (const float*)d_in[2];
    const float* wo = (const float*)d_in[3];
    float* out = (float*)d_out;

    char* ws = (char*)d_ws;
    // ws layout (34,078,720 B total):
    //   [0, 8.4MB)     xn bf16 [16][256][1024]; reused later as attnout
    //   [8.4, 33.6MB)  qkv bf16 [16][768][1024]
    //   [33.6, ...)    w_qkv bf16, w_out bf16
    unsigned short* xn  = (unsigned short*)(ws);
    unsigned short* qkv = (unsigned short*)(ws + 8388608);
    unsigned short* wqb = (unsigned short*)(ws + 33554432);
    unsigned short* wob = (unsigned short*)(ws + 33947648);

    prep_kernel<<<1024, 256, 0, stream>>>(wq, wo, wqb, wob);
    ln_kernel<<<dim3(64, 16), 256, 0, stream>>>(x, g, xn);
    gemm_kernel<1><<<dim3(12, 16, 16), 256, 0, stream>>>(wqb, xn, (void*)qkv, nullptr, 768);
    l2norm_kernel<<<dim3(16, 8, 16), 256, 0, stream>>>(qkv);
    attn_kernel<<<dim3(16, 4, 16), 256, 0, stream>>>(qkv, xn /* = attnout */);
    gemm_kernel<0><<<dim3(4, 16, 16), 256, 0, stream>>>(wob, xn, (void*)out, x, 256);
}

// Round 2
// 91.160 us; speedup vs baseline: 1.3236x; 1.3236x over previous
//
#include <hip/hip_runtime.h>
#include <hip/hip_bf16.h>

typedef short short4v __attribute__((ext_vector_type(4)));
typedef float float4v __attribute__((ext_vector_type(4)));
typedef __bf16 bf16x8 __attribute__((ext_vector_type(8)));

typedef __attribute__((address_space(1))) const unsigned int g_uint;
typedef __attribute__((address_space(3))) unsigned int lds_uint;

__device__ __forceinline__ unsigned short f2bf(float f) {
    union { float f; unsigned int i; } t;
    t.f = f;
    unsigned int u = t.i;
    u += 0x7fffu + ((u >> 16) & 1u);   // round-to-nearest-even
    return (unsigned short)(u >> 16);
}

// async global->LDS, 16B per lane; lds ptr must be wave-uniform (base + lane*16 implicit)
__device__ __forceinline__ void gload_lds16(const unsigned short* g, unsigned short* l) {
    __builtin_amdgcn_global_load_lds((g_uint*)g, (lds_uint*)l, 16, 0, 0);
}

// read 8 contiguous bf16 (b128) from a swizzled [64][64] u16 tile:
// element (row, 8*slot + i) lives at u16 offset row*64 + ((slot ^ (row&7))<<3) + i
__device__ __forceinline__ bf16x8 frag128(const unsigned short* t, int row, int slot) {
    return *reinterpret_cast<const bf16x8*>(
        reinterpret_cast<const char*>(t) + row * 128 + (((slot ^ (row & 7)) << 4)));
}

__device__ __forceinline__ float4v mfma32(bf16x8 a, bf16x8 b, float4v c) {
    return __builtin_amdgcn_mfma_f32_16x16x32_bf16(a, b, c, 0, 0, 0);
}

// ---------------------------------------------------------------------------
// Kernel 0: weights f32 -> bf16
// ---------------------------------------------------------------------------
__global__ __launch_bounds__(256) void prep_kernel(const float* __restrict__ wq,
                                                   const float* __restrict__ wo,
                                                   unsigned short* __restrict__ wqb,
                                                   unsigned short* __restrict__ wob) {
    int i = blockIdx.x * 256 + threadIdx.x;   // 262144 total
    if (i < 196608) wqb[i] = f2bf(wq[i]);
    else            wob[i - 196608] = f2bf(wo[i - 196608]);
}

// ---------------------------------------------------------------------------
// Kernel 1: channel LayerNorm.  x[b][c=256][pix] f32 -> xn_T[b][pix][c] bf16.
// block 256 = 64 px * 4 c-groups; grid (16 pixgroups, 16 b)
// ---------------------------------------------------------------------------
__global__ __launch_bounds__(256) void ln_kernel(const float* __restrict__ x,
                                                 const float* __restrict__ g,
                                                 unsigned short* __restrict__ xnT) {
    __shared__ float red[2][4][64];
    const int tid = threadIdx.x;
    const int p = tid & 63, cg = tid >> 6;
    const int b = blockIdx.y;
    const int pix = blockIdx.x * 64 + p;
    const float* xb = x + ((size_t)b << 18) + pix;

    float v[64];
    float s = 0.f, q = 0.f;
    #pragma unroll
    for (int cc = 0; cc < 64; ++cc) {
        v[cc] = xb[(cg * 64 + cc) << 10];
        s += v[cc]; q += v[cc] * v[cc];
    }
    red[0][cg][p] = s; red[1][cg][p] = q;
    __syncthreads();
    float ts = red[0][0][p] + red[0][1][p] + red[0][2][p] + red[0][3][p];
    float tq = red[1][0][p] + red[1][1][p] + red[1][2][p] + red[1][3][p];
    float mean = ts * (1.f / 256.f);
    float var  = tq * (1.f / 256.f) - mean * mean;
    float rstd = rsqrtf(var + 1e-5f);
    float bias = -mean * rstd;

    unsigned short* dst = xnT + (((size_t)b << 10) + pix) * 256 + cg * 64;
    #pragma unroll
    for (int cc = 0; cc < 64; cc += 8) {
        union { uint4 u; unsigned short s[8]; } pk;
        #pragma unroll
        for (int j = 0; j < 8; ++j)
            pk.s[j] = f2bf(fmaf(v[cc + j], rstd, bias) * g[cg * 64 + cc + j]);
        *reinterpret_cast<uint4*>(dst + cc) = pk.u;
    }
}

// ---------------------------------------------------------------------------
// Kernel 2: QKV GEMM with fused L2-norm + relayout.
// grid (12 m-blocks, 16 pix-blocks, 16 b).  Tile 64x64, BK=64, double-buffered.
// m<8 (q,k heads): C^T form (A=xn_T, B=W), D[pix][oc], l2norm epilogue.
//   m 0..3 -> qhat[b][h][pix][d]; m 4..7 -> khat swizzled [j][d] tiles.
// m>=8 (v heads): C form (A=W, B=xn_T), D[oc][pix] -> v swizzled [d][j] tiles.
// ---------------------------------------------------------------------------
__global__ __launch_bounds__(256) void qkv_gemm(const unsigned short* __restrict__ xnT,
                                                const unsigned short* __restrict__ wqkv,
                                                unsigned short* __restrict__ qhat,
                                                unsigned short* __restrict__ khatT,
                                                unsigned short* __restrict__ vT) {
    __shared__ __align__(16) unsigned short sW[8192];
    __shared__ __align__(16) unsigned short sX[8192];
    const int tid = threadIdx.x, lane = tid & 63, w = tid >> 6;
    const int l16 = lane & 15, g = lane >> 4;
    const int m = blockIdx.x, pb = blockIdx.y, b = blockIdx.z;
    const unsigned short* Wbase = wqkv + m * 64 * 256;
    const unsigned short* Xbase = xnT + (((size_t)b << 10) + pb * 64) * 256;

    const int srow = (lane >> 3);          // 0..7 within instruction
    const int sslot = lane & 7;

    auto stage = [&](int buf, int k0) {
        #pragma unroll
        for (int ii = 0; ii < 2; ++ii) {
            int inst = w + 4 * ii;         // 0..7, covers 8 rows each
            int row = inst * 8 + srow;
            int src = row * 256 + k0 + 8 * (sslot ^ (row & 7));
            gload_lds16(Wbase + src, &sW[buf * 4096 + inst * 512]);
            gload_lds16(Xbase + src, &sX[buf * 4096 + inst * 512]);
        }
    };

    float4v acc[4] = {{0,0,0,0},{0,0,0,0},{0,0,0,0},{0,0,0,0}};
    const bool qk = (m < 8);

    stage(0, 0);
    __syncthreads();
    for (int ks = 0; ks < 4; ++ks) {
        if (ks < 3) stage((ks + 1) & 1, (ks + 1) * 64);
        const unsigned short* Wt = &sW[(ks & 1) * 4096];
        const unsigned short* Xt = &sX[(ks & 1) * 4096];
        #pragma unroll
        for (int kk = 0; kk < 2; ++kk) {
            bf16x8 aF = frag128(qk ? Xt : Wt, 16 * w + l16, 4 * kk + g);
            #pragma unroll
            for (int jt = 0; jt < 4; ++jt) {
                bf16x8 bF = frag128(qk ? Wt : Xt, 16 * jt + l16, 4 * kk + g);
                acc[jt] = mfma32(aF, bF, acc[jt]);
            }
        }
        __syncthreads();
    }

    if (qk) {
        // D[pix = pb*64 + 16w + 4g + r][oc = 16jt + l16]; norm over oc (=d within head)
        float rn[4];
        #pragma unroll
        for (int r = 0; r < 4; ++r) {
            float s = acc[0][r]*acc[0][r] + acc[1][r]*acc[1][r]
                    + acc[2][r]*acc[2][r] + acc[3][r]*acc[3][r];
            s += __shfl_xor(s, 1, 64);
            s += __shfl_xor(s, 2, 64);
            s += __shfl_xor(s, 4, 64);
            s += __shfl_xor(s, 8, 64);
            rn[r] = rsqrtf(fmaxf(s, 1e-24f));
        }
        int h = m & 3;
        if (m < 4) {
            unsigned short* qb = qhat + (((size_t)(b * 4 + h) << 10) + pb * 64 + 16 * w) * 64;
            #pragma unroll
            for (int jt = 0; jt < 4; ++jt)
                #pragma unroll
                for (int r = 0; r < 4; ++r)
                    qb[(4 * g + r) * 64 + 16 * jt + l16] = f2bf(acc[jt][r] * rn[r]);
        } else {
            unsigned short* kb = khatT + ((size_t)((b * 4 + h) * 16 + pb)) * 4096;
            #pragma unroll
            for (int jt = 0; jt < 4; ++jt)
                #pragma unroll
                for (int r = 0; r < 4; ++r) {
                    int j = 16 * w + 4 * g + r;
                    int d = 16 * jt + l16;
                    kb[j * 64 + (((d >> 3) ^ (j & 7)) << 3) + (d & 7)] = f2bf(acc[jt][r] * rn[r]);
                }
        }
    } else {
        // D[oc = 16w + 4g + r][pix]; v tile [d][j] swizzled
        int h = m - 8;
        unsigned short* vb = vT + ((size_t)((b * 4 + h) * 16 + pb)) * 4096;
        #pragma unroll
        for (int jt = 0; jt < 4; ++jt)
            #pragma unroll
            for (int r = 0; r < 4; ++r) {
                int d = 16 * w + 4 * g + r;
                int j = 16 * jt + l16;
                vb[d * 64 + (((j >> 3) ^ (d & 7)) << 3) + (j & 7)] = f2bf(acc[jt][r]);
            }
    }
}

// ---------------------------------------------------------------------------
// Kernel 3: flash attention.  grid (8 qblocks, 4 h, 16 b), block 256 (4 waves).
// Wave handles 2 i-tiles (32 queries).  K/V tiles pre-swizzled in global ->
// linear global_load_lds staging, double-buffered, 1 barrier/tile.
// QK^T: K=32 MFMA (S^T = K*Q^T).  PV: K=16 MFMA (O^T = V*P^T), P^T from regs.
// Output O_T[b][pix][h*64+d] via LDS transpose.
// ---------------------------------------------------------------------------
__global__ __launch_bounds__(256) void attn_kernel(const unsigned short* __restrict__ qhat,
                                                   const unsigned short* __restrict__ khatT,
                                                   const unsigned short* __restrict__ vT,
                                                   unsigned short* __restrict__ oT) {
    __shared__ __align__(16) unsigned short smem[16384];   // 2 x (K 4096 + V 4096)
    const int tid = threadIdx.x, lane = tid & 63, w = tid >> 6;
    const int l16 = lane & 15, g = lane >> 4;
    const int qb = blockIdx.x, h = blockIdx.y, b = blockIdx.z;

    const unsigned short* Qg = qhat + (((size_t)(b * 4 + h) << 10) + qb * 128) * 64;
    const unsigned short* Kt = khatT + ((size_t)((b * 4 + h) * 16)) * 4096;
    const unsigned short* Vt = vT    + ((size_t)((b * 4 + h) * 16)) * 4096;

    // Q fragments: B-operand, col i = l16, k = d = 32*ds + 8*g + [0..8)
    bf16x8 bq[2][2];
    #pragma unroll
    for (int it = 0; it < 2; ++it)
        #pragma unroll
        for (int ds = 0; ds < 2; ++ds)
            bq[it][ds] = *reinterpret_cast<const bf16x8*>(
                Qg + (32 * w + 16 * it + l16) * 64 + 32 * ds + 8 * g);

    auto stage = [&](int buf, int t) {
        const unsigned short* ks = Kt + (size_t)t * 4096;
        const unsigned short* vs = Vt + (size_t)t * 4096;
        unsigned short* kb = &smem[buf * 8192];
        unsigned short* vb = &smem[buf * 8192 + 4096];
        #pragma unroll
        for (int ii = 0; ii < 2; ++ii) {
            int off = (w + 4 * ii) * 512;
            gload_lds16(ks + off + lane * 8, kb + off);
            gload_lds16(vs + off + lane * 8, vb + off);
        }
    };

    float m_run[2] = {-1e30f, -1e30f};
    float lsum[2] = {0.f, 0.f};
    float4v oacc[2][4] = {};

    stage(0, 0);
    __syncthreads();

    for (int t = 0; t < 16; ++t) {
        if (t < 15) stage((t + 1) & 1, t + 1);
        const unsigned short* kb = &smem[(t & 1) * 8192];
        const unsigned short* vb = &smem[(t & 1) * 8192 + 4096];

        // S^T[j][i] = sum_d K[j][d] Q^T[d][i]
        float4v st[2][4] = {};
        #pragma unroll
        for (int ds = 0; ds < 2; ++ds)
            #pragma unroll
            for (int jt = 0; jt < 4; ++jt) {
                bf16x8 ak = frag128(kb, 16 * jt + l16, 4 * ds + g);
                #pragma unroll
                for (int it = 0; it < 2; ++it)
                    st[it][jt] = mfma32(ak, bq[it][ds], st[it][jt]);
            }

        short4v pf[2][4];
        #pragma unroll
        for (int it = 0; it < 2; ++it) {
            float mloc = -1e30f;
            #pragma unroll
            for (int jt = 0; jt < 4; ++jt)
                mloc = fmaxf(mloc, fmaxf(fmaxf(st[it][jt][0], st[it][jt][1]),
                                         fmaxf(st[it][jt][2], st[it][jt][3])));
            mloc = fmaxf(mloc, __shfl_xor(mloc, 16, 64));
            mloc = fmaxf(mloc, __shfl_xor(mloc, 32, 64));
            float m_new = fmaxf(m_run[it], 8.f * mloc);
            float alpha = __expf(m_run[it] - m_new);
            m_run[it] = m_new;

            float psum = 0.f;
            #pragma unroll
            for (int jt = 0; jt < 4; ++jt) {
                float p0 = __expf(__fmaf_rn(8.f, st[it][jt][0], -m_new));
                float p1 = __expf(__fmaf_rn(8.f, st[it][jt][1], -m_new));
                float p2 = __expf(__fmaf_rn(8.f, st[it][jt][2], -m_new));
                float p3 = __expf(__fmaf_rn(8.f, st[it][jt][3], -m_new));
                psum += p0 + p1 + p2 + p3;
                short4v tt;
                tt[0] = (short)f2bf(p0); tt[1] = (short)f2bf(p1);
                tt[2] = (short)f2bf(p2); tt[3] = (short)f2bf(p3);
                pf[it][jt] = tt;
            }
            psum += __shfl_xor(psum, 16, 64);
            psum += __shfl_xor(psum, 32, 64);
            lsum[it] = lsum[it] * alpha + psum;
            #pragma unroll
            for (int dt = 0; dt < 4; ++dt) {
                oacc[it][dt][0] *= alpha; oacc[it][dt][1] *= alpha;
                oacc[it][dt][2] *= alpha; oacc[it][dt][3] *= alpha;
            }
        }

        // O^T[d][i] += V^T[d][j] P^T[j][i]  (K=16 path, proven layout)
        #pragma unroll
        for (int jt = 0; jt < 4; ++jt)
            #pragma unroll
            for (int dt = 0; dt < 4; ++dt) {
                int row = 16 * dt + l16;
                const char* ap = reinterpret_cast<const char*>(vb) + row * 128
                               + (((2 * jt + (g >> 1)) ^ (row & 7)) << 4) + 8 * (g & 1);
                short4v av = *reinterpret_cast<const short4v*>(ap);
                #pragma unroll
                for (int it = 0; it < 2; ++it)
                    oacc[it][dt] = __builtin_amdgcn_mfma_f32_16x16x16bf16_1k(
                        av, pf[it][jt], oacc[it][dt], 0, 0, 0);
            }
        __syncthreads();
    }

    // transpose O through LDS -> O_T[pix][h*64+d], vectorized 16B stores
    unsigned short* OL = smem;   // [128][72] u16
    #pragma unroll
    for (int it = 0; it < 2; ++it) {
        float inv = 1.f / lsum[it];
        int irow = 32 * w + 16 * it + l16;
        #pragma unroll
        for (int dt = 0; dt < 4; ++dt)
            #pragma unroll
            for (int r = 0; r < 4; ++r)
                OL[irow * 72 + 16 * dt + 4 * g + r] = f2bf(oacc[it][dt][r] * inv);
    }
    __syncthreads();
    {
        int row = tid >> 1, half = tid & 1;
        unsigned short* dst = oT + (((size_t)b << 10) + qb * 128 + row) * 256 + h * 64 + half * 32;
        const unsigned short* src = OL + row * 72 + half * 32;
        #pragma unroll
        for (int q = 0; q < 4; ++q)
            *reinterpret_cast<uint4*>(dst + q * 8) =
                *reinterpret_cast<const uint4*>(src + q * 8);
    }
}

// ---------------------------------------------------------------------------
// Kernel 4: out projection + residual.  grid (4 m, 16 pix, 16 b).
// C form: A = w_out[256][256], B = O_T tiles.  D[oc][pix] f32 + x.
// ---------------------------------------------------------------------------
__global__ __launch_bounds__(256) void out_gemm(const unsigned short* __restrict__ oT,
                                                const unsigned short* __restrict__ wout,
                                                const float* __restrict__ x,
                                                float* __restrict__ out) {
    __shared__ __align__(16) unsigned short sW[8192];
    __shared__ __align__(16) unsigned short sX[8192];
    const int tid = threadIdx.x, lane = tid & 63, w = tid >> 6;
    const int l16 = lane & 15, g = lane >> 4;
    const int m = blockIdx.x, pb = blockIdx.y, b = blockIdx.z;
    const unsigned short* Wbase = wout + m * 64 * 256;
    const unsigned short* Xbase = oT + (((size_t)b << 10) + pb * 64) * 256;

    const int srow = (lane >> 3);
    const int sslot = lane & 7;

    auto stage = [&](int buf, int k0) {
        #pragma unroll
        for (int ii = 0; ii < 2; ++ii) {
            int inst = w + 4 * ii;
            int row = inst * 8 + srow;
            int src = row * 256 + k0 + 8 * (sslot ^ (row & 7));
            gload_lds16(Wbase + src, &sW[buf * 4096 + inst * 512]);
            gload_lds16(Xbase + src, &sX[buf * 4096 + inst * 512]);
        }
    };

    float4v acc[4] = {{0,0,0,0},{0,0,0,0},{0,0,0,0},{0,0,0,0}};
    stage(0, 0);
    __syncthreads();
    for (int ks = 0; ks < 4; ++ks) {
        if (ks < 3) stage((ks + 1) & 1, (ks + 1) * 64);
        const unsigned short* Wt = &sW[(ks & 1) * 4096];
        const unsigned short* Xt = &sX[(ks & 1) * 4096];
        #pragma unroll
        for (int kk = 0; kk < 2; ++kk) {
            bf16x8 aF = frag128(Wt, 16 * w + l16, 4 * kk + g);
            #pragma unroll
            for (int jt = 0; jt < 4; ++jt) {
                bf16x8 bF = frag128(Xt, 16 * jt + l16, 4 * kk + g);
                acc[jt] = mfma32(aF, bF, acc[jt]);
            }
        }
        __syncthreads();
    }

    // D[oc = m*64 + 16w + 4g + r][pix = pb*64 + 16jt + l16] + residual
    #pragma unroll
    for (int jt = 0; jt < 4; ++jt)
        #pragma unroll
        for (int r = 0; r < 4; ++r) {
            size_t idx = ((size_t)b << 18) + (size_t)(m * 64 + 16 * w + 4 * g + r) * 1024
                       + pb * 64 + 16 * jt + l16;
            out[idx] = acc[jt][r] + x[idx];
        }
}

// ---------------------------------------------------------------------------
extern "C" void kernel_launch(void* const* d_in, const int* in_sizes, int n_in,
                              void* d_out, int out_size, void* d_ws, size_t ws_size,
                              hipStream_t stream) {
    const float* x  = (const float*)d_in[0];
    const float* g  = (const float*)d_in[1];
    const float* wq = (const float*)d_in[2];
    const float* wo = (const float*)d_in[3];
    float* out = (float*)d_out;

    char* ws = (char*)d_ws;
    // ws layout (34,078,720 B):
    //   [0, 8.4MB)        xn_T bf16 [16][1024][256]; reused as O_T after qkv_gemm
    //   [8.4, 16.8MB)     qhat bf16 [16][4][1024][64]
    //   [16.8, 25.2MB)    khat swizzled tiles [16][4][16][64*64]
    //   [25.2, 33.6MB)    v swizzled tiles    [16][4][16][64*64]
    //   [33.6MB, ...)     w_qkv bf16, w_out bf16
    unsigned short* xnT   = (unsigned short*)(ws);
    unsigned short* qhat  = (unsigned short*)(ws + 8388608);
    unsigned short* khatT = (unsigned short*)(ws + 16777216);
    unsigned short* vT    = (unsigned short*)(ws + 25165824);
    unsigned short* wqb   = (unsigned short*)(ws + 33554432);
    unsigned short* wob   = (unsigned short*)(ws + 33947648);
    unsigned short* oT    = xnT;   // reuse

    prep_kernel<<<1024, 256, 0, stream>>>(wq, wo, wqb, wob);
    ln_kernel<<<dim3(16, 16), 256, 0, stream>>>(x, g, xnT);
    qkv_gemm<<<dim3(12, 16, 16), 256, 0, stream>>>(xnT, wqb, qhat, khatT, vT);
    attn_kernel<<<dim3(8, 4, 16), 256, 0, stream>>>(qhat, khatT, vT, oT);
    out_gemm<<<dim3(4, 16, 16), 256, 0, stream>>>(oT, wob, x, out);
}